// Round 11
// baseline (64.387 us; speedup 1.0000x reference)
//
#include <hip/hip_runtime.h>
#include <math.h>

// st_VQEmbedding via MFMA, register-direct A-path (no LDS, no barriers,
// no manual waitcnt in the k-loop).
// z [65536,64] f32, emb [512,64] f32 -> out = emb[argmin_k (x2-2dot)+e2],
// straight-through (q+x)-x. dot via bf16 2-term split MFMA (al*bh + ah*bl +
// ah*bh, fp32 accum) -- bit-identical chains/term order/tie-break to
// R5/R7/R8/R10 (all passed absmax 0.0).
//
// R11: LDS staging was structurally losing (R7/R8 barrier-lockstep, R9
// counted-vmcnt race, R10 vmcnt(0) serialization). Register-direct A-loads
// (R5's bit-exact path) + explicit 1-chunk-ahead register prefetch; the
// compiler's dependency-tracked vmcnt handles the waits robustly (spills
// included). PPB=64 / 4 point-tiles per wave makes per-chunk compute
// (~24 MFMA + 80 VALU ~ 280 cyc) cover the ~200cyc L2 latency.

constexpr int K     = 512;
constexpr int D     = 64;
constexpr int NPTS  = 16 * 4096;   // 65536
constexpr int BLOCK = 256;
constexpr int PPB   = 64;          // points per block (4 tiles per wave)
constexpr int CHUNK = 16;          // codes per chunk = one MFMA code-tile
constexpr int NCH   = 8;           // chunks per wave (128 codes, K-split x4)

typedef __attribute__((ext_vector_type(8))) short  short8;
typedef __attribute__((ext_vector_type(4))) float  f32x4;

__device__ inline unsigned short bf16_rne(float f) {
    unsigned u = __builtin_bit_cast(unsigned, f);
    u += 0x7fffu + ((u >> 16) & 1u);
    return (unsigned short)(u >> 16);
}
__device__ inline float bf16_f32(unsigned short h) {
    unsigned u = (unsigned)h << 16;
    return __builtin_bit_cast(float, u);
}

// ---- prep: one thread per code. e2 (exact chain) + bf16 hi/lo split,
// LINEAR granule layout: g = k*8 + s  (s = d/8; no swizzle needed). ----
__global__ void prep_emb(const float* __restrict__ emb,
                         float* __restrict__ e2,
                         short8* __restrict__ wsHi,
                         short8* __restrict__ wsLo)
{
    const int k = blockIdx.x * 128 + threadIdx.x;   // 4 blocks x 128 = 512
    const float4* row = reinterpret_cast<const float4*>(emb + k * D);
    float v[64];
    #pragma unroll
    for (int i = 0; i < 16; ++i) {
        float4 q = row[i];
        v[4*i+0] = q.x; v[4*i+1] = q.y; v[4*i+2] = q.z; v[4*i+3] = q.w;
    }
    float acc = 0.0f;
    {
        #pragma clang fp contract(off)
        #pragma unroll
        for (int d = 0; d < 64; ++d) acc = acc + v[d] * v[d];
    }
    e2[k] = acc;
    #pragma unroll
    for (int s = 0; s < 8; ++s) {
        short8 hi, lo;
        #pragma unroll
        for (int e = 0; e < 8; ++e) {
            const float f = v[s * 8 + e];
            const unsigned short h = bf16_rne(f);
            const float r = f - bf16_f32(h);      // exact (Sterbenz)
            hi[e] = (short)h;
            lo[e] = (short)bf16_rne(r);
        }
        wsHi[k * 8 + s] = hi;
        wsLo[k * 8 + s] = lo;
    }
}

// ---- main: register-direct MFMA argmin + gather ---------------------------
__global__ __launch_bounds__(BLOCK, 3)
void vq_mfma(const float* __restrict__ z,
             const float* __restrict__ emb,
             const float* __restrict__ e2,
             const short8* __restrict__ wsHi,
             const short8* __restrict__ wsLo,
             float* __restrict__ out)
{
    __shared__ float bestw[4][PPB];
    __shared__ int   bidxw[4][PPB];
    __shared__ int   bfin[PPB];

    const int tid = threadIdx.x;
    const int wq  = __builtin_amdgcn_readfirstlane(tid >> 6);  // wave 0..3
    const int l   = tid & 63;
    const int col = l & 15;              // point-in-tile / code-in-tile
    const int kg  = (l >> 4) & 3;        // k-group / code-row group

    const float4* zf4 = reinterpret_cast<const float4*>(z);
    const float4* ef4 = reinterpret_cast<const float4*>(emb);
    float4*       of4 = reinterpret_cast<float4*>(out);

    const int base = blockIdx.x * PPB;

    // ---- x2: one point per lane (pt = base + l), exact unfused chain ----
    float x2c = 0.0f;
    {
        #pragma clang fp contract(off)
        #pragma unroll
        for (int i = 0; i < 16; ++i) {
            float4 q = zf4[(base + l) * 16 + i];
            x2c = x2c + q.x * q.x;
            x2c = x2c + q.y * q.y;
            x2c = x2c + q.z * q.z;
            x2c = x2c + q.w * q.w;
        }
    }
    float x2v[4];
    #pragma unroll
    for (int p = 0; p < 4; ++p) x2v[p] = __shfl(x2c, p * 16 + col);

    // ---- B-frags for 4 point-tiles (identical build chain to R8/R10) ----
    short8 bh[4][2], bl[4][2];
    #pragma unroll
    for (int p = 0; p < 4; ++p) {
        const int pt = base + p * 16 + col;
        #pragma unroll
        for (int kt = 0; kt < 2; ++kt) {
            const float4 va = zf4[pt * 16 + kt * 8 + kg * 2];
            const float4 vb = zf4[pt * 16 + kt * 8 + kg * 2 + 1];
            const float xs[8] = {va.x, va.y, va.z, va.w, vb.x, vb.y, vb.z, vb.w};
            #pragma unroll
            for (int e = 0; e < 8; ++e) {
                const unsigned short h = bf16_rne(xs[e]);
                const float r = xs[e] - bf16_f32(h);   // exact
                bh[p][kt][e] = (short)h;
                bl[p][kt][e] = (short)bf16_rne(r);
            }
        }
    }

    // ---- k-loop: wq's 128 codes, 8 chunks, 1-chunk-ahead reg prefetch ----
    // lane's A granules for chunk c: g = (wq*128 + c*16 + col)*8 + kt*4 + kg
    const int off0 = col * 8 + kg;        // kt = 0
    const int off1 = col * 8 + 4 + kg;    // kt = 1

    short8 aH0[2], aH1[2], aL0[2], aL1[2];
    f32x4  e2r[2];

    auto loadA = [&](int c, int s) {
        const int gb = (wq * 128 + c * CHUNK) * 8;
        aH0[s] = wsHi[gb + off0];
        aH1[s] = wsHi[gb + off1];
        aL0[s] = wsLo[gb + off0];
        aL1[s] = wsLo[gb + off1];
        e2r[s] = *reinterpret_cast<const f32x4*>(e2 + wq * 128 + c * CHUNK + kg * 4);
    };

    loadA(0, 0);

    float best0 = INFINITY, best1 = INFINITY, best2 = INFINITY, best3 = INFINITY;
    int   bi0 = 0, bi1 = 0, bi2 = 0, bi3 = 0;

    #pragma unroll
    for (int c = 0; c < NCH; ++c) {
        const int s = c & 1;
        if (c + 1 < NCH) loadA(c + 1, s ^ 1);   // prefetch; compiler tracks deps

        const short8 ah0 = aH0[s], ah1 = aH1[s], al0 = aL0[s], al1 = aL1[s];

        f32x4 acc0 = {0.f,0.f,0.f,0.f}, acc1 = {0.f,0.f,0.f,0.f};
        f32x4 acc2 = {0.f,0.f,0.f,0.f}, acc3 = {0.f,0.f,0.f,0.f};
        // same term order as R5/R7/R8/R10: per kt {al*bh, ah*bl, ah*bh}
        acc0 = __builtin_amdgcn_mfma_f32_16x16x32_bf16(al0, bh[0][0], acc0, 0, 0, 0);
        acc0 = __builtin_amdgcn_mfma_f32_16x16x32_bf16(ah0, bl[0][0], acc0, 0, 0, 0);
        acc0 = __builtin_amdgcn_mfma_f32_16x16x32_bf16(ah0, bh[0][0], acc0, 0, 0, 0);
        acc0 = __builtin_amdgcn_mfma_f32_16x16x32_bf16(al1, bh[0][1], acc0, 0, 0, 0);
        acc0 = __builtin_amdgcn_mfma_f32_16x16x32_bf16(ah1, bl[0][1], acc0, 0, 0, 0);
        acc0 = __builtin_amdgcn_mfma_f32_16x16x32_bf16(ah1, bh[0][1], acc0, 0, 0, 0);

        acc1 = __builtin_amdgcn_mfma_f32_16x16x32_bf16(al0, bh[1][0], acc1, 0, 0, 0);
        acc1 = __builtin_amdgcn_mfma_f32_16x16x32_bf16(ah0, bl[1][0], acc1, 0, 0, 0);
        acc1 = __builtin_amdgcn_mfma_f32_16x16x32_bf16(ah0, bh[1][0], acc1, 0, 0, 0);
        acc1 = __builtin_amdgcn_mfma_f32_16x16x32_bf16(al1, bh[1][1], acc1, 0, 0, 0);
        acc1 = __builtin_amdgcn_mfma_f32_16x16x32_bf16(ah1, bl[1][1], acc1, 0, 0, 0);
        acc1 = __builtin_amdgcn_mfma_f32_16x16x32_bf16(ah1, bh[1][1], acc1, 0, 0, 0);

        acc2 = __builtin_amdgcn_mfma_f32_16x16x32_bf16(al0, bh[2][0], acc2, 0, 0, 0);
        acc2 = __builtin_amdgcn_mfma_f32_16x16x32_bf16(ah0, bl[2][0], acc2, 0, 0, 0);
        acc2 = __builtin_amdgcn_mfma_f32_16x16x32_bf16(ah0, bh[2][0], acc2, 0, 0, 0);
        acc2 = __builtin_amdgcn_mfma_f32_16x16x32_bf16(al1, bh[2][1], acc2, 0, 0, 0);
        acc2 = __builtin_amdgcn_mfma_f32_16x16x32_bf16(ah1, bl[2][1], acc2, 0, 0, 0);
        acc2 = __builtin_amdgcn_mfma_f32_16x16x32_bf16(ah1, bh[2][1], acc2, 0, 0, 0);

        acc3 = __builtin_amdgcn_mfma_f32_16x16x32_bf16(al0, bh[3][0], acc3, 0, 0, 0);
        acc3 = __builtin_amdgcn_mfma_f32_16x16x32_bf16(ah0, bl[3][0], acc3, 0, 0, 0);
        acc3 = __builtin_amdgcn_mfma_f32_16x16x32_bf16(ah0, bh[3][0], acc3, 0, 0, 0);
        acc3 = __builtin_amdgcn_mfma_f32_16x16x32_bf16(al1, bh[3][1], acc3, 0, 0, 0);
        acc3 = __builtin_amdgcn_mfma_f32_16x16x32_bf16(ah1, bl[3][1], acc3, 0, 0, 0);
        acc3 = __builtin_amdgcn_mfma_f32_16x16x32_bf16(ah1, bh[3][1], acc3, 0, 0, 0);

        const int   kglob = wq * 128 + c * CHUNK + kg * 4;
        const f32x4 e2v   = e2r[s];
        float dt;
        dt = (x2v[0] - 2.0f * acc0[0]) + e2v[0]; if (dt < best0) { best0 = dt; bi0 = kglob + 0; }
        dt = (x2v[0] - 2.0f * acc0[1]) + e2v[1]; if (dt < best0) { best0 = dt; bi0 = kglob + 1; }
        dt = (x2v[0] - 2.0f * acc0[2]) + e2v[2]; if (dt < best0) { best0 = dt; bi0 = kglob + 2; }
        dt = (x2v[0] - 2.0f * acc0[3]) + e2v[3]; if (dt < best0) { best0 = dt; bi0 = kglob + 3; }
        dt = (x2v[1] - 2.0f * acc1[0]) + e2v[0]; if (dt < best1) { best1 = dt; bi1 = kglob + 0; }
        dt = (x2v[1] - 2.0f * acc1[1]) + e2v[1]; if (dt < best1) { best1 = dt; bi1 = kglob + 1; }
        dt = (x2v[1] - 2.0f * acc1[2]) + e2v[2]; if (dt < best1) { best1 = dt; bi1 = kglob + 2; }
        dt = (x2v[1] - 2.0f * acc1[3]) + e2v[3]; if (dt < best1) { best1 = dt; bi1 = kglob + 3; }
        dt = (x2v[2] - 2.0f * acc2[0]) + e2v[0]; if (dt < best2) { best2 = dt; bi2 = kglob + 0; }
        dt = (x2v[2] - 2.0f * acc2[1]) + e2v[1]; if (dt < best2) { best2 = dt; bi2 = kglob + 1; }
        dt = (x2v[2] - 2.0f * acc2[2]) + e2v[2]; if (dt < best2) { best2 = dt; bi2 = kglob + 2; }
        dt = (x2v[2] - 2.0f * acc2[3]) + e2v[3]; if (dt < best2) { best2 = dt; bi2 = kglob + 3; }
        dt = (x2v[3] - 2.0f * acc3[0]) + e2v[0]; if (dt < best3) { best3 = dt; bi3 = kglob + 0; }
        dt = (x2v[3] - 2.0f * acc3[1]) + e2v[1]; if (dt < best3) { best3 = dt; bi3 = kglob + 1; }
        dt = (x2v[3] - 2.0f * acc3[2]) + e2v[2]; if (dt < best3) { best3 = dt; bi3 = kglob + 2; }
        dt = (x2v[3] - 2.0f * acc3[3]) + e2v[3]; if (dt < best3) { best3 = dt; bi3 = kglob + 3; }
    }

    // combine 4 kg-groups within the wave: lexicographic (dist, idx)
    #pragma unroll
    for (int off = 16; off < 64; off <<= 1) {
        float ov; int oi;
        ov = __shfl_xor(best0, off); oi = __shfl_xor(bi0, off);
        if (ov < best0 || (ov == best0 && oi < bi0)) { best0 = ov; bi0 = oi; }
        ov = __shfl_xor(best1, off); oi = __shfl_xor(bi1, off);
        if (ov < best1 || (ov == best1 && oi < bi1)) { best1 = ov; bi1 = oi; }
        ov = __shfl_xor(best2, off); oi = __shfl_xor(bi2, off);
        if (ov < best2 || (ov == best2 && oi < bi2)) { best2 = ov; bi2 = oi; }
        ov = __shfl_xor(best3, off); oi = __shfl_xor(bi3, off);
        if (ov < best3 || (ov == best3 && oi < bi3)) { best3 = ov; bi3 = oi; }
    }
    if (l < 16) {
        bestw[wq][ 0 + col] = best0;  bidxw[wq][ 0 + col] = bi0;
        bestw[wq][16 + col] = best1;  bidxw[wq][16 + col] = bi1;
        bestw[wq][32 + col] = best2;  bidxw[wq][32 + col] = bi2;
        bestw[wq][48 + col] = best3;  bidxw[wq][48 + col] = bi3;
    }
    __syncthreads();

    // combine 4 wave K-quarters: ascending wave = ascending k; strict <
    if (tid < PPB) {
        float bb = bestw[0][tid];
        int   ii = bidxw[0][tid];
        #pragma unroll
        for (int ww = 1; ww < 4; ++ww) {
            const float ob = bestw[ww][tid];
            const int   oi = bidxw[ww][tid];
            if (ob < bb) { bb = ob; ii = oi; }
        }
        bfin[tid] = ii;
    }
    __syncthreads();

    // dense epilogue: lane-linear float4 stores, straight-through (q+x)-x
    #pragma unroll
    for (int i = 0; i < (PPB * 16) / BLOCK; ++i) {   // 4 iters
        const int idx = i * BLOCK + tid;
        const int p   = idx >> 4;
        const int j   = idx & 15;
        const float4 q = ef4[bfin[p] * 16 + j];
        const float4 x = zf4[(base + p) * 16 + j];
        float4 o;
        o.x = (q.x + x.x) - x.x;
        o.y = (q.y + x.y) - x.y;
        o.z = (q.z + x.z) - x.z;
        o.w = (q.w + x.w) - x.w;
        of4[(base + p) * 16 + j] = o;
    }
}

extern "C" void kernel_launch(void* const* d_in, const int* in_sizes, int n_in,
                              void* d_out, int out_size, void* d_ws, size_t ws_size,
                              hipStream_t stream) {
    const float* z   = (const float*)d_in[0];
    const float* emb = (const float*)d_in[1];
    float* out = (float*)d_out;

    // ws: e2 f32[512] (2KB) | wsHi short8[4096] (64KB) | wsLo short8[4096] (64KB)
    float*  e2   = (float*)d_ws;
    short8* wsHi = (short8*)((char*)d_ws + 2048);
    short8* wsLo = (short8*)((char*)d_ws + 2048 + 65536);

    prep_emb<<<4, 128, 0, stream>>>(emb, e2, wsHi, wsLo);
    vq_mfma<<<NPTS / PPB, BLOCK, 0, stream>>>(z, emb, e2, wsHi, wsLo, out);
}

// Round 12
// 36.919 us; speedup vs baseline: 1.7440x; 1.7440x over previous
//
#include <hip/hip_runtime.h>
#include <math.h>

// st_VQEmbedding via LDS-staged MFMA GEMM (R8 structure, higher occupancy).
// z [65536,64] f32, emb [512,64] f32 -> out = emb[argmin_k (x2-2dot)+e2],
// straight-through (q+x)-x. dot via bf16 2-term split MFMA (al*bh + ah*bl +
// ah*bh, fp32 accum) -- bit-identical chains/term order/tie-break to
// R5/R7/R8/R10 (all passed absmax 0.0).
//
// R12: R8 ran grid 512 = 2 blocks/CU; barrier drains had only one other
// block to hide behind (R10 counters: correlated wave stalls). PPB 128->64
// -> grid 1024 -> 4 blocks/CU (LDS 34.5KB x4 = 138KB fits), each wave owns
// ONE 16-point tile scanning all codes. Tree-argmin per tile (identical
// first-index semantics, 4x shorter serial chain). VGPR ~70, no spills.

constexpr int K      = 512;
constexpr int D      = 64;
constexpr int NPTS   = 16 * 4096;    // 65536
constexpr int BLOCK  = 256;
constexpr int PPB    = 64;           // points per block (4 waves x 16)
constexpr int CHUNK  = 64;           // codes per LDS chunk
constexpr int NCHUNK = K / CHUNK;    // 8
constexpr int TPC    = CHUNK / 16;   // 4 code-tiles per chunk
constexpr int GPC    = CHUNK * 8;    // 512 16B-granules per chunk per array

typedef __attribute__((ext_vector_type(8))) short  short8;
typedef __attribute__((ext_vector_type(4))) float  f32x4;

#define AS_G (const __attribute__((address_space(1))) void*)
#define AS_L (__attribute__((address_space(3))) void*)

__device__ inline unsigned short bf16_rne(float f) {
    unsigned u = __builtin_bit_cast(unsigned, f);
    u += 0x7fffu + ((u >> 16) & 1u);
    return (unsigned short)(u >> 16);
}
__device__ inline float bf16_f32(unsigned short h) {
    unsigned u = (unsigned)h << 16;
    return __builtin_bit_cast(float, u);
}

// ---- prep: e2 (exact chain) + bf16 hi/lo split, written pre-swizzled ------
// thread t: code k = t>>3, d-slot s = t&7 (d = s*8..s*8+7).
// ws granule index = (k>>6)*GPC + (k&63)*8 + (s ^ (k&7))   [identical to R8]
__global__ void prep_emb(const float* __restrict__ emb,
                         float* __restrict__ e2,
                         short8* __restrict__ wsHi,
                         short8* __restrict__ wsLo)
{
    const int gid = blockIdx.x * 256 + threadIdx.x;   // 0..4095
    const int k = gid >> 3;
    const int s = gid & 7;

    const float4* row = reinterpret_cast<const float4*>(emb + k * D);
    float v[64];
    #pragma unroll
    for (int i = 0; i < 16; ++i) {
        float4 q = row[i];
        v[4*i+0] = q.x; v[4*i+1] = q.y; v[4*i+2] = q.z; v[4*i+3] = q.w;
    }
    if (s == 0) {   // exact sequential unfused e2 (same chain as R1-R10)
        float acc = 0.0f;
        {
            #pragma clang fp contract(off)
            #pragma unroll
            for (int d = 0; d < 64; ++d) acc = acc + v[d] * v[d];
        }
        e2[k] = acc;
    }
    short8 hi, lo;
    #pragma unroll
    for (int e = 0; e < 8; ++e) {
        const float f = v[s * 8 + e];
        const unsigned short h = bf16_rne(f);
        const float r = f - bf16_f32(h);          // exact (Sterbenz)
        hi[e] = (short)h;
        lo[e] = (short)bf16_rne(r);
    }
    const int slot = (k >> 6) * GPC + (k & 63) * 8 + (s ^ (k & 7));
    wsHi[slot] = hi;
    wsLo[slot] = lo;
}

// ---- main: LDS-staged MFMA argmin + gather ---------------------------------
__global__ __launch_bounds__(BLOCK, 4)
void vq_mfma(const float* __restrict__ z,
             const float* __restrict__ emb,
             const float* __restrict__ e2,
             const short8* __restrict__ wsHi,
             const short8* __restrict__ wsLo,
             float* __restrict__ out)
{
    __shared__ short8 Ahi[2][GPC];    // 2 x 8 KiB
    __shared__ short8 Alo[2][GPC];    // 2 x 8 KiB
    __shared__ float4 e2L[K / 4];     // 2 KiB
    __shared__ int    bidx_s[PPB];

    const int tid = threadIdx.x;
    const int w   = tid >> 6;         // wave -> owns point-tile w
    const int l   = tid & 63;
    const int col = l & 15;           // point within tile
    const int kg  = l >> 4;           // k-group / code-row group

    const float4* zf4 = reinterpret_cast<const float4*>(z);
    const float4* ef4 = reinterpret_cast<const float4*>(emb);
    float4*       of4 = reinterpret_cast<float4*>(out);

    const int base = blockIdx.x * PPB;
    const int pt   = base + w * 16 + col;   // this lane's point

    // stage chunk c (64 codes, hi+lo) into buffer b: pure linear copy,
    // source already in LDS-image (swizzled) order.
    auto stage = [&](int c, int b) {
        const short8* sH = wsHi + c * GPC;
        const short8* sL = wsLo + c * GPC;
        #pragma unroll
        for (int i = 0; i < 2; ++i) {
            const int f = i * 256 + tid;
            __builtin_amdgcn_global_load_lds(AS_G(sH + f),
                                             AS_L(&Ahi[b][f]), 16, 0, 0);
            __builtin_amdgcn_global_load_lds(AS_G(sL + f),
                                             AS_L(&Alo[b][f]), 16, 0, 0);
        }
    };

    stage(0, 0);   // in flight during x2 / B-frag build
    if (tid < K / 4)   // e2 -> LDS, lane-linear 16B granules
        __builtin_amdgcn_global_load_lds(AS_G(e2 + tid * 4),
                                         AS_L(&e2L[tid]), 16, 0, 0);

    // ---- x2 for this lane's point, exact sequential unfused chain ----
    float x2v = 0.0f;
    {
        #pragma clang fp contract(off)
        #pragma unroll
        for (int i = 0; i < 16; ++i) {
            float4 q = zf4[pt * 16 + i];
            x2v = x2v + q.x * q.x;
            x2v = x2v + q.y * q.y;
            x2v = x2v + q.z * q.z;
            x2v = x2v + q.w * q.w;
        }
    }

    // ---- B-frags for this wave's point-tile (identical build to R8) ----
    short8 bh[2], bl[2];
    #pragma unroll
    for (int kt = 0; kt < 2; ++kt) {
        const float4 va = zf4[pt * 16 + kt * 8 + kg * 2];
        const float4 vb = zf4[pt * 16 + kt * 8 + kg * 2 + 1];
        const float xs[8] = {va.x, va.y, va.z, va.w, vb.x, vb.y, vb.z, vb.w};
        #pragma unroll
        for (int e = 0; e < 8; ++e) {
            const unsigned short h = bf16_rne(xs[e]);
            const float r = xs[e] - bf16_f32(h);   // exact
            bh[kt][e] = (short)h;
            bl[kt][e] = (short)bf16_rne(r);
        }
    }

    __syncthreads();   // chunk 0 + e2L staged

    float best = INFINITY;
    int   bi   = 0;
    int   b    = 0;

    for (int c = 0; c < NCHUNK; ++c) {
        if (c + 1 < NCHUNK) stage(c + 1, b ^ 1);

        #pragma unroll
        for (int t = 0; t < TPC; ++t) {
            // swizzled A slots: code_local = t*16+col, sidx = (kt*4+kg)^(col&7)
            const int slot0 = ((t * 16 + col) << 3) | (kg ^ (col & 7)); // kt=0
            const short8 ah0 = Ahi[b][slot0];
            const short8 ah1 = Ahi[b][slot0 ^ 4];                        // kt=1
            const short8 al0 = Alo[b][slot0];
            const short8 al1 = Alo[b][slot0 ^ 4];

            f32x4 acc = {0.f, 0.f, 0.f, 0.f};
            // same term order as R5/R7/R8: per kt {al*bh, ah*bl, ah*bh}
            acc = __builtin_amdgcn_mfma_f32_16x16x32_bf16(al0, bh[0], acc, 0, 0, 0);
            acc = __builtin_amdgcn_mfma_f32_16x16x32_bf16(ah0, bl[0], acc, 0, 0, 0);
            acc = __builtin_amdgcn_mfma_f32_16x16x32_bf16(ah0, bh[0], acc, 0, 0, 0);
            acc = __builtin_amdgcn_mfma_f32_16x16x32_bf16(al1, bh[1], acc, 0, 0, 0);
            acc = __builtin_amdgcn_mfma_f32_16x16x32_bf16(ah1, bl[1], acc, 0, 0, 0);
            acc = __builtin_amdgcn_mfma_f32_16x16x32_bf16(ah1, bh[1], acc, 0, 0, 0);

            const int   kbase = c * CHUNK + t * 16 + kg * 4;
            const float4 e2v  = e2L[kbase >> 2];   // broadcast-pattern ds_read
            const float d0 = (x2v - 2.0f * acc[0]) + e2v.x;
            const float d1 = (x2v - 2.0f * acc[1]) + e2v.y;
            const float d2 = (x2v - 2.0f * acc[2]) + e2v.z;
            const float d3 = (x2v - 2.0f * acc[3]) + e2v.w;

            // tree argmin, identical first-index semantics to the sequential
            // strict-< scan (ties resolve to lower k at every node):
            float mv01 = d0; int mi01 = kbase + 0;
            if (d1 < mv01) { mv01 = d1; mi01 = kbase + 1; }
            float mv23 = d2; int mi23 = kbase + 2;
            if (d3 < mv23) { mv23 = d3; mi23 = kbase + 3; }
            float mv = mv01; int mi = mi01;
            if (mv23 < mv) { mv = mv23; mi = mi23; }
            if (mv < best) { best = mv; bi = mi; }
        }
        __syncthreads();   // drains stage vmcnt + all waves done with buf b
        b ^= 1;
    }

    // combine 4 kg-groups (lanes sharing a column): lexicographic (dist, idx)
    #pragma unroll
    for (int off = 16; off < 64; off <<= 1) {
        const float ov = __shfl_xor(best, off);
        const int   oi = __shfl_xor(bi,   off);
        if (ov < best || (ov == best && oi < bi)) { best = ov; bi = oi; }
    }
    if (l < 16) bidx_s[w * 16 + col] = bi;
    __syncthreads();

    // dense epilogue: lane-linear float4 stores, straight-through (q+x)-x
    #pragma unroll
    for (int i = 0; i < (PPB * 16) / BLOCK; ++i) {   // 4 iters
        const int idx = i * BLOCK + tid;
        const int p   = idx >> 4;
        const int j   = idx & 15;
        const float4 q = ef4[bidx_s[p] * 16 + j];
        const float4 x = zf4[(base + p) * 16 + j];
        float4 o;
        o.x = (q.x + x.x) - x.x;
        o.y = (q.y + x.y) - x.y;
        o.z = (q.z + x.z) - x.z;
        o.w = (q.w + x.w) - x.w;
        of4[(base + p) * 16 + j] = o;
    }
}

extern "C" void kernel_launch(void* const* d_in, const int* in_sizes, int n_in,
                              void* d_out, int out_size, void* d_ws, size_t ws_size,
                              hipStream_t stream) {
    const float* z   = (const float*)d_in[0];
    const float* emb = (const float*)d_in[1];
    float* out = (float*)d_out;

    // ws: e2 f32[512] (2KB) | wsHi short8[4096] (64KB) | wsLo short8[4096] (64KB)
    float*  e2   = (float*)d_ws;
    short8* wsHi = (short8*)((char*)d_ws + 2048);
    short8* wsLo = (short8*)((char*)d_ws + 2048 + 65536);

    prep_emb<<<16, 256, 0, stream>>>(emb, e2, wsHi, wsLo);
    vq_mfma<<<NPTS / PPB, BLOCK, 0, stream>>>(z, emb, e2, wsHi, wsLo, out);
}

// Round 13
// 36.877 us; speedup vs baseline: 1.7460x; 1.0012x over previous
//
#include <hip/hip_runtime.h>
#include <math.h>

// st_VQEmbedding via LDS-staged MFMA GEMM (R12 structure + ILP argmin).
// z [65536,64] f32, emb [512,64] f32 -> out = emb[argmin_k (x2-2dot)+e2],
// straight-through (q+x)-x. dot via bf16 2-term split MFMA (al*bh + ah*bl +
// ah*bh, fp32 accum) -- bit-identical chains/term order/tie-break to
// R5/R7/R8/R12 (all passed absmax 0.0).
//
// R13: R7/R8/R12 all land ~37us regardless of occupancy/tile-count -> the
// bound is the per-wave SERIAL spine: each k-tile's best/bi update depends
// on the previous tile (ds_read -> 6-dep-MFMA -> dist -> cmp), ~700cyc x 32
// iters that TLP can't hide. Fix: independent (best,idx) slot per tile
// position t=0..3 (named scalars, static) -> tiles fully independent, 4
// MFMA chains in flight; slots lex-merged after the loop (provably same
// first-index semantics: each stream is ascending-k, lex merge picks
// lowest k among streams at the global min).

constexpr int K      = 512;
constexpr int D      = 64;
constexpr int NPTS   = 16 * 4096;    // 65536
constexpr int BLOCK  = 256;
constexpr int PPB    = 64;           // points per block (4 waves x 16)
constexpr int CHUNK  = 64;           // codes per LDS chunk
constexpr int NCHUNK = K / CHUNK;    // 8
constexpr int GPC    = CHUNK * 8;    // 512 16B-granules per chunk per array

typedef __attribute__((ext_vector_type(8))) short  short8;
typedef __attribute__((ext_vector_type(4))) float  f32x4;

#define AS_G (const __attribute__((address_space(1))) void*)
#define AS_L (__attribute__((address_space(3))) void*)

__device__ inline unsigned short bf16_rne(float f) {
    unsigned u = __builtin_bit_cast(unsigned, f);
    u += 0x7fffu + ((u >> 16) & 1u);
    return (unsigned short)(u >> 16);
}
__device__ inline float bf16_f32(unsigned short h) {
    unsigned u = (unsigned)h << 16;
    return __builtin_bit_cast(float, u);
}

// ---- prep: e2 (exact chain) + bf16 hi/lo split, written pre-swizzled ------
// thread t: code k = t>>3, d-slot s = t&7 (d = s*8..s*8+7).
// ws granule index = (k>>6)*GPC + (k&63)*8 + (s ^ (k&7))   [identical to R12]
__global__ void prep_emb(const float* __restrict__ emb,
                         float* __restrict__ e2,
                         short8* __restrict__ wsHi,
                         short8* __restrict__ wsLo)
{
    const int gid = blockIdx.x * 256 + threadIdx.x;   // 0..4095
    const int k = gid >> 3;
    const int s = gid & 7;

    const float4* row = reinterpret_cast<const float4*>(emb + k * D);
    float v[64];
    #pragma unroll
    for (int i = 0; i < 16; ++i) {
        float4 q = row[i];
        v[4*i+0] = q.x; v[4*i+1] = q.y; v[4*i+2] = q.z; v[4*i+3] = q.w;
    }
    if (s == 0) {   // exact sequential unfused e2 (same chain as R1-R12)
        float acc = 0.0f;
        {
            #pragma clang fp contract(off)
            #pragma unroll
            for (int d = 0; d < 64; ++d) acc = acc + v[d] * v[d];
        }
        e2[k] = acc;
    }
    short8 hi, lo;
    #pragma unroll
    for (int e = 0; e < 8; ++e) {
        const float f = v[s * 8 + e];
        const unsigned short h = bf16_rne(f);
        const float r = f - bf16_f32(h);          // exact (Sterbenz)
        hi[e] = (short)h;
        lo[e] = (short)bf16_rne(r);
    }
    const int slot = (k >> 6) * GPC + (k & 63) * 8 + (s ^ (k & 7));
    wsHi[slot] = hi;
    wsLo[slot] = lo;
}

// ---- main: LDS-staged MFMA argmin + gather ---------------------------------
__global__ __launch_bounds__(BLOCK, 4)
void vq_mfma(const float* __restrict__ z,
             const float* __restrict__ emb,
             const float* __restrict__ e2,
             const short8* __restrict__ wsHi,
             const short8* __restrict__ wsLo,
             float* __restrict__ out)
{
    __shared__ short8 Ahi[2][GPC];    // 2 x 8 KiB
    __shared__ short8 Alo[2][GPC];    // 2 x 8 KiB
    __shared__ float4 e2L[K / 4];     // 2 KiB
    __shared__ int    bidx_s[PPB];

    const int tid = threadIdx.x;
    const int w   = tid >> 6;         // wave -> owns point-tile w
    const int l   = tid & 63;
    const int col = l & 15;           // point within tile
    const int kg  = l >> 4;           // k-group / code-row group

    const float4* zf4 = reinterpret_cast<const float4*>(z);
    const float4* ef4 = reinterpret_cast<const float4*>(emb);
    float4*       of4 = reinterpret_cast<float4*>(out);

    const int base = blockIdx.x * PPB;
    const int pt   = base + w * 16 + col;   // this lane's point

    // stage chunk c (64 codes, hi+lo) into buffer b: pure linear copy,
    // source already in LDS-image (swizzled) order.
    auto stage = [&](int c, int b) {
        const short8* sH = wsHi + c * GPC;
        const short8* sL = wsLo + c * GPC;
        #pragma unroll
        for (int i = 0; i < 2; ++i) {
            const int f = i * 256 + tid;
            __builtin_amdgcn_global_load_lds(AS_G(sH + f),
                                             AS_L(&Ahi[b][f]), 16, 0, 0);
            __builtin_amdgcn_global_load_lds(AS_G(sL + f),
                                             AS_L(&Alo[b][f]), 16, 0, 0);
        }
    };

    stage(0, 0);   // in flight during x2 / B-frag build
    if (tid < K / 4)   // e2 -> LDS, lane-linear 16B granules
        __builtin_amdgcn_global_load_lds(AS_G(e2 + tid * 4),
                                         AS_L(&e2L[tid]), 16, 0, 0);

    // ---- x2 for this lane's point, exact sequential unfused chain ----
    float x2v = 0.0f;
    {
        #pragma clang fp contract(off)
        #pragma unroll
        for (int i = 0; i < 16; ++i) {
            float4 q = zf4[pt * 16 + i];
            x2v = x2v + q.x * q.x;
            x2v = x2v + q.y * q.y;
            x2v = x2v + q.z * q.z;
            x2v = x2v + q.w * q.w;
        }
    }

    // ---- B-frags for this wave's point-tile (identical build to R12) ----
    short8 bh[2], bl[2];
    #pragma unroll
    for (int kt = 0; kt < 2; ++kt) {
        const float4 va = zf4[pt * 16 + kt * 8 + kg * 2];
        const float4 vb = zf4[pt * 16 + kt * 8 + kg * 2 + 1];
        const float xs[8] = {va.x, va.y, va.z, va.w, vb.x, vb.y, vb.z, vb.w};
        #pragma unroll
        for (int e = 0; e < 8; ++e) {
            const unsigned short h = bf16_rne(xs[e]);
            const float r = xs[e] - bf16_f32(h);   // exact
            bh[kt][e] = (short)h;
            bl[kt][e] = (short)bf16_rne(r);
        }
    }

    __syncthreads();   // chunk 0 + e2L staged

    // Independent argmin slot per tile-position t (named scalars: no dynamic
    // indexing -> registers). Each stream sees ascending k.
    float bv0 = INFINITY, bv1 = INFINITY, bv2 = INFINITY, bv3 = INFINITY;
    int   ix0 = 0, ix1 = 0, ix2 = 0, ix3 = 0;
    int   b = 0;

    for (int c = 0; c < NCHUNK; ++c) {
        if (c + 1 < NCHUNK) stage(c + 1, b ^ 1);

        #pragma unroll
        for (int t = 0; t < 4; ++t) {
            // swizzled A slots: code_local = t*16+col, sidx = (kt*4+kg)^(col&7)
            const int slot0 = ((t * 16 + col) << 3) | (kg ^ (col & 7)); // kt=0
            const short8 ah0 = Ahi[b][slot0];
            const short8 ah1 = Ahi[b][slot0 ^ 4];                        // kt=1
            const short8 al0 = Alo[b][slot0];
            const short8 al1 = Alo[b][slot0 ^ 4];

            f32x4 acc = {0.f, 0.f, 0.f, 0.f};
            // same term order as R5/R7/R8/R12: per kt {al*bh, ah*bl, ah*bh}
            acc = __builtin_amdgcn_mfma_f32_16x16x32_bf16(al0, bh[0], acc, 0, 0, 0);
            acc = __builtin_amdgcn_mfma_f32_16x16x32_bf16(ah0, bl[0], acc, 0, 0, 0);
            acc = __builtin_amdgcn_mfma_f32_16x16x32_bf16(ah0, bh[0], acc, 0, 0, 0);
            acc = __builtin_amdgcn_mfma_f32_16x16x32_bf16(al1, bh[1], acc, 0, 0, 0);
            acc = __builtin_amdgcn_mfma_f32_16x16x32_bf16(ah1, bl[1], acc, 0, 0, 0);
            acc = __builtin_amdgcn_mfma_f32_16x16x32_bf16(ah1, bh[1], acc, 0, 0, 0);

            const int   kbase = c * CHUNK + t * 16 + kg * 4;
            const float4 e2v  = e2L[kbase >> 2];   // broadcast-pattern ds_read
            const float d0 = (x2v - 2.0f * acc[0]) + e2v.x;
            const float d1 = (x2v - 2.0f * acc[1]) + e2v.y;
            const float d2 = (x2v - 2.0f * acc[2]) + e2v.z;
            const float d3 = (x2v - 2.0f * acc[3]) + e2v.w;

            // tree argmin within the tile (ties -> lower k at every node),
            // then update THIS tile-position's private slot.
            float mv01 = d0; int mi01 = kbase + 0;
            if (d1 < mv01) { mv01 = d1; mi01 = kbase + 1; }
            float mv23 = d2; int mi23 = kbase + 2;
            if (d3 < mv23) { mv23 = d3; mi23 = kbase + 3; }
            float mv = mv01; int mi = mi01;
            if (mv23 < mv) { mv = mv23; mi = mi23; }
            if (t == 0) { if (mv < bv0) { bv0 = mv; ix0 = mi; } }
            if (t == 1) { if (mv < bv1) { bv1 = mv; ix1 = mi; } }
            if (t == 2) { if (mv < bv2) { bv2 = mv; ix2 = mi; } }
            if (t == 3) { if (mv < bv3) { bv3 = mv; ix3 = mi; } }
        }
        __syncthreads();   // drains stage vmcnt + all waves done with buf b
        b ^= 1;
    }

    // merge the 4 independent slots: lexicographic (val, idx) -> identical
    // first-index semantics (each stream ascending-k; lex picks lowest k
    // among streams achieving the global min).
    float best = bv0; int bi = ix0;
    if (bv1 < best || (bv1 == best && ix1 < bi)) { best = bv1; bi = ix1; }
    if (bv2 < best || (bv2 == best && ix2 < bi)) { best = bv2; bi = ix2; }
    if (bv3 < best || (bv3 == best && ix3 < bi)) { best = bv3; bi = ix3; }

    // combine 4 kg-groups (lanes sharing a column): lexicographic (dist, idx)
    #pragma unroll
    for (int off = 16; off < 64; off <<= 1) {
        const float ov = __shfl_xor(best, off);
        const int   oi = __shfl_xor(bi,   off);
        if (ov < best || (ov == best && oi < bi)) { best = ov; bi = oi; }
    }
    if (l < 16) bidx_s[w * 16 + col] = bi;
    __syncthreads();

    // dense epilogue: lane-linear float4 stores, straight-through (q+x)-x
    #pragma unroll
    for (int i = 0; i < (PPB * 16) / BLOCK; ++i) {   // 4 iters
        const int idx = i * BLOCK + tid;
        const int p   = idx >> 4;
        const int j   = idx & 15;
        const float4 q = ef4[bidx_s[p] * 16 + j];
        const float4 x = zf4[(base + p) * 16 + j];
        float4 o;
        o.x = (q.x + x.x) - x.x;
        o.y = (q.y + x.y) - x.y;
        o.z = (q.z + x.z) - x.z;
        o.w = (q.w + x.w) - x.w;
        of4[(base + p) * 16 + j] = o;
    }
}

extern "C" void kernel_launch(void* const* d_in, const int* in_sizes, int n_in,
                              void* d_out, int out_size, void* d_ws, size_t ws_size,
                              hipStream_t stream) {
    const float* z   = (const float*)d_in[0];
    const float* emb = (const float*)d_in[1];
    float* out = (float*)d_out;

    // ws: e2 f32[512] (2KB) | wsHi short8[4096] (64KB) | wsLo short8[4096] (64KB)
    float*  e2   = (float*)d_ws;
    short8* wsHi = (short8*)((char*)d_ws + 2048);
    short8* wsLo = (short8*)((char*)d_ws + 2048 + 65536);

    prep_emb<<<16, 256, 0, stream>>>(emb, e2, wsHi, wsLo);
    vq_mfma<<<NPTS / PPB, BLOCK, 0, stream>>>(z, emb, e2, wsHi, wsLo, out);
}